// Round 1
// baseline (72.400 us; speedup 1.0000x reference)
//
#include <hip/hip_runtime.h>
#include <hip/hip_bf16.h>

// Problem constants (from reference): B=8, k=8 bits, H=W=64 -> N=4096, d_v=32.
#define B_SZ   8
#define KBITS  8
#define NPOS   4096      // H*W
#define DV     32
#define NCODE  256
#define PARTS  4         // histogram partials per batch

// ---------------------------------------------------------------------------
// Kernel 1: threshold z -> 8-bit codes, and per-(batch,part) histograms.
// grid = B*PARTS blocks, 256 threads. Each block handles NPOS/PARTS positions.
// Each block writes its OWN partial histogram -> no zero-init of ws needed.
// ---------------------------------------------------------------------------
__global__ __launch_bounds__(256) void k_codes_hist(const float* __restrict__ z,
                                                    unsigned char* __restrict__ codes,
                                                    int* __restrict__ hist) {
    const int b = blockIdx.x >> 2;        // batch
    const int p = blockIdx.x & (PARTS - 1);
    __shared__ int h[NCODE];
    h[threadIdx.x] = 0;
    __syncthreads();

    const float* zb = z + (size_t)b * KBITS * NPOS;
    const int base = p * (NPOS / PARTS);
    for (int i = threadIdx.x; i < NPOS / PARTS; i += 256) {
        const int n = base + i;
        int code = 0;
#pragma unroll
        for (int bit = 0; bit < KBITS; ++bit)
            code |= (zb[bit * NPOS + n] > 0.5f) ? (1 << bit) : 0;
        codes[b * NPOS + n] = (unsigned char)code;
        atomicAdd(&h[code], 1);
    }
    __syncthreads();
    hist[blockIdx.x * NCODE + threadIdx.x] = h[threadIdx.x];
}

// ---------------------------------------------------------------------------
// Kernel 2: build Ttab[b][d][c] = (sum_v cnt[v]*w(pop(c^v))*V[v][d])
//                               / (sum_v cnt[v]*w(pop(c^v)))
// grid = B * 8(d-chunks of 4) * 4(c-chunks of 64) = 256 blocks, 256 threads.
// Thread layout: c fastest (tid&63) so the final store is fully coalesced.
// Per wave, dl = tid>>6 is constant -> all LDS reads are same-address
// broadcasts (conflict-free).
// ---------------------------------------------------------------------------
__global__ __launch_bounds__(256) void k_table(const int* __restrict__ hist,
                                               const float* __restrict__ V,
                                               const float* __restrict__ temp,
                                               float* __restrict__ Ttab) {
    const int bid = blockIdx.x;           // 0..255
    const int b   = bid >> 5;             // 0..7
    const int dch = (bid >> 2) & 7;       // d base = dch*4
    const int cch = bid & 3;              // c base = cch*64

    __shared__ float Vld[NCODE * 4];      // V[v][dch*4 + j], 4 KB
    __shared__ float cntf[NCODE];
    __shared__ float wl[KBITS + 1];

    const int tid = threadIdx.x;
    for (int idx = tid; idx < NCODE * 4; idx += 256) {
        const int v = idx >> 2, j = idx & 3;
        Vld[idx] = V[v * DV + dch * 4 + j];
    }
    {
        int s = 0;
#pragma unroll
        for (int p = 0; p < PARTS; ++p)
            s += hist[(b * PARTS + p) * NCODE + tid];
        cntf[tid] = (float)s;
    }
    if (tid <= KBITS) {
        const float Tc = fmaxf(temp[0], 0.1f);
        wl[tid] = expf(-(float)tid / Tc);
    }
    __syncthreads();

    const int c  = cch * 64 + (tid & 63);
    const int dl = tid >> 6;              // 0..3 (wave-uniform)
    float accS = 0.f, accV = 0.f;
#pragma unroll 8
    for (int v = 0; v < NCODE; ++v) {
        const float cw = cntf[v] * wl[__popc(c ^ v)];
        accS += cw;
        accV = fmaf(cw, Vld[v * 4 + dl], accV);
    }
    const int d = dch * 4 + dl;
    Ttab[((b * DV + d) * NCODE) + c] = accV / accS;   // coalesced 256B/wave
}

// ---------------------------------------------------------------------------
// Kernel 3: out[b][d][n] = Ttab[b][d][codes[b][n]]
// grid = B*DV = 256 blocks, 256 threads. Table row in LDS; uchar4 code loads,
// float4 coalesced stores.
// ---------------------------------------------------------------------------
__global__ __launch_bounds__(256) void k_out(const unsigned char* __restrict__ codes,
                                             const float* __restrict__ Ttab,
                                             float* __restrict__ out) {
    const int b = blockIdx.x >> 5;        // 0..7
    const int d = blockIdx.x & 31;        // 0..31
    __shared__ float tab[NCODE];
    tab[threadIdx.x] = Ttab[((b * DV + d) * NCODE) + threadIdx.x];
    __syncthreads();

    const uchar4* c4 = (const uchar4*)(codes + (size_t)b * NPOS);
    float4* o4 = (float4*)(out + (size_t)(b * DV + d) * NPOS);
    for (int i = threadIdx.x; i < NPOS / 4; i += 256) {
        const uchar4 cc = c4[i];
        float4 r;
        r.x = tab[cc.x];
        r.y = tab[cc.y];
        r.z = tab[cc.z];
        r.w = tab[cc.w];
        o4[i] = r;
    }
}

// ---------------------------------------------------------------------------
extern "C" void kernel_launch(void* const* d_in, const int* in_sizes, int n_in,
                              void* d_out, int out_size, void* d_ws, size_t ws_size,
                              hipStream_t stream) {
    const float* z    = (const float*)d_in[0];   // (B,8,64,64) fp32
    const float* temp = (const float*)d_in[1];   // scalar
    const float* V    = (const float*)d_in[2];   // (256,32) fp32
    float* out        = (float*)d_out;           // (B,32,64,64) fp32

    char* ws = (char*)d_ws;
    unsigned char* codes = (unsigned char*)ws;                 // 32768 B
    int*   hist = (int*)(ws + B_SZ * NPOS);                    // 32768 B (B*PARTS*256*4)
    float* Ttab = (float*)(ws + B_SZ * NPOS + B_SZ * PARTS * NCODE * 4); // 262144 B

    k_codes_hist<<<B_SZ * PARTS, 256, 0, stream>>>(z, codes, hist);
    k_table<<<B_SZ * 8 * 4, 256, 0, stream>>>(hist, V, temp, Ttab);
    k_out<<<B_SZ * DV, 256, 0, stream>>>(codes, Ttab, out);
}

// Round 2
// 66.065 us; speedup vs baseline: 1.0959x; 1.0959x over previous
//
#include <hip/hip_runtime.h>
#include <hip/hip_bf16.h>

// Problem constants: B=8, k=8 bits, H=W=64 -> N=4096, d_v=32.
#define B_SZ   8
#define KBITS  8
#define NPOS   4096
#define DV     32
#define NCODE  256
#define NSLICE 32              // n-slices per batch; grid = B_SZ*NSLICE = 256 blocks

// ---------------------------------------------------------------------------
// Single fused kernel. Each block serves (batch b, slice s of 128 positions):
//   A) codes + histogram for the WHOLE batch (redundant per block; z slice is
//      128 KB and L2-resident across the 32 blocks of the same batch)
//   B) T[v][d] = cnt[v]*V[v][d] (d<32), T[v][32] = cnt[v]
//   C) 8 butterfly stages: T[u] += a*T[u^2^s]  (tensor-product expansion of
//      w(pop(c^v)) = a^pop, a = exp(-1/Tc)) -> T[c] = sum_v a^pop(c^v) X[v]
//   D) normalize: T[c][d] /= T[c][32]
//   E) out[b][d][n] = T[code_n][d] for the block's 128-position slice
// ---------------------------------------------------------------------------
__global__ __launch_bounds__(1024) void k_fused(const float* __restrict__ z,
                                                const float* __restrict__ V,
                                                const float* __restrict__ temp,
                                                float* __restrict__ out) {
    const int b = blockIdx.x >> 5;        // batch
    const int s = blockIdx.x & (NSLICE - 1);
    const int tid = threadIdx.x;

    __shared__ unsigned int codes_u[NPOS / 4];   // 4 KB, 4 packed codes per u32
    __shared__ int h[NCODE];                     // 1 KB
    __shared__ float T[NCODE][DV + 1];           // 33.8 KB, stride 33 (odd -> bank-friendly)

    if (tid < NCODE) h[tid] = 0;
    __syncthreads();

    // ---- A: codes + histogram (1024 threads x 4 positions = 4096) ----
    {
        const float4* z4 = (const float4*)(z + (size_t)b * KBITS * NPOS);
        unsigned int c0 = 0, c1 = 0, c2 = 0, c3 = 0;
#pragma unroll
        for (int bit = 0; bit < KBITS; ++bit) {
            const float4 f = z4[bit * (NPOS / 4) + tid];
            c0 |= (unsigned)(f.x > 0.5f) << bit;
            c1 |= (unsigned)(f.y > 0.5f) << bit;
            c2 |= (unsigned)(f.z > 0.5f) << bit;
            c3 |= (unsigned)(f.w > 0.5f) << bit;
        }
        codes_u[tid] = c0 | (c1 << 8) | (c2 << 16) | (c3 << 24);
        atomicAdd(&h[c0], 1);
        atomicAdd(&h[c1], 1);
        atomicAdd(&h[c2], 1);
        atomicAdd(&h[c3], 1);
    }
    __syncthreads();

    // ---- B: seed table with cnt[v]*V[v][d]; extra col 32 holds cnt[v] ----
    for (int idx = tid; idx < NCODE * DV; idx += 1024) {
        const int v = idx >> 5, d = idx & 31;
        T[v][d] = (float)h[v] * V[v * DV + d];   // V read coalesced
    }
    if (tid < NCODE) T[tid][DV] = (float)h[tid];

    // ---- C: butterfly over code bits ----
    const float a = expf(-1.0f / fmaxf(temp[0], 0.1f));
#pragma unroll 1
    for (int st = 0; st < KBITS; ++st) {
        __syncthreads();
        for (int i = tid; i < (DV + 1) * 128; i += 1024) {   // 33*128 = 4224 items
            const int c = i >> 7;                 // 0..32
            const int p = i & 127;                // pair index
            const int lo = p & ((1 << st) - 1);
            const int v0 = ((p >> st) << (st + 1)) | lo;
            const int v1 = v0 | (1 << st);
            const float t0 = T[v0][c], t1 = T[v1][c];
            T[v0][c] = fmaf(a, t1, t0);
            T[v1][c] = fmaf(a, t0, t1);
        }
    }
    __syncthreads();

    // ---- D: normalize by the S column ----
    if (tid < NCODE) T[tid][DV] = 1.0f / T[tid][DV];
    __syncthreads();
    for (int idx = tid; idx < NCODE * DV; idx += 1024) {
        const int v = idx >> 5, d = idx & 31;     // d varies across lanes -> conflict-free
        T[v][d] *= T[v][DV];
    }
    __syncthreads();

    // ---- E: gather + coalesced store of the block's 128-position slice ----
    {
        const unsigned char* cbytes = (const unsigned char*)codes_u;
        const int nl = tid & 127;                 // position within slice
        const int dg = tid >> 7;                  // 0..7
        const int code = cbytes[s * 128 + nl];
        float* ob = out + (size_t)(b * DV) * NPOS + s * 128 + nl;
#pragma unroll
        for (int j = 0; j < 4; ++j) {
            const int d = dg + 8 * j;
            ob[(size_t)d * NPOS] = T[code][d];    // 64 consecutive floats per wave
        }
    }
}

// ---------------------------------------------------------------------------
extern "C" void kernel_launch(void* const* d_in, const int* in_sizes, int n_in,
                              void* d_out, int out_size, void* d_ws, size_t ws_size,
                              hipStream_t stream) {
    const float* z    = (const float*)d_in[0];   // (B,8,64,64) fp32
    const float* temp = (const float*)d_in[1];   // scalar
    const float* V    = (const float*)d_in[2];   // (256,32) fp32
    float* out        = (float*)d_out;           // (B,32,64,64) fp32

    k_fused<<<B_SZ * NSLICE, 1024, 0, stream>>>(z, V, temp, out);
}

// Round 3
// 65.978 us; speedup vs baseline: 1.0973x; 1.0013x over previous
//
#include <hip/hip_runtime.h>
#include <hip/hip_bf16.h>

// Problem constants: B=8, k=8 bits, H=W=64 -> N=4096, d_v=32.
#define B_SZ   8
#define KBITS  8
#define NPOS   4096
#define DV     32
#define NCODE  256
#define NSLICE 32              // n-slices per batch; grid = B_SZ*NSLICE = 256 blocks

// ---------------------------------------------------------------------------
// Single fused kernel, register/shuffle butterfly version.
// Block = (batch b, slice s of 128 positions), 1024 threads.
//   A) codes + histogram for the whole batch (z slice L2-resident; LDS atomics)
//   B) seed per-lane: half-wave hw = tid>>5 owns d-column hw; lane l = tid&31
//      holds v = 8l..8l+7:  val[j] = cnt[v]*V[v][d],  cnt[j] = cnt[v]
//   C) butterfly T[u] += a*T[u^2^st]:
//        st 0..2  -> in-register pairs (j, j^2^st)
//        st 3..7  -> __shfl_xor masks 1,2,4,8,16 (inside half-wave, no LDS)
//      a = exp(-1/max(temp,0.1));  w(pop(c^v)) = a^pop  (tensor product)
//   D) normalize lane-locally (lane holds both T[c][d] and S[c]), write to LDS
//   E) gather T[code][d] -> one float4 store per thread (coalesced 512B runs)
// Barriers: 3 (vs 11 before); butterfly LDS traffic: 0 (vs 540 KB/block).
// ---------------------------------------------------------------------------
__global__ __launch_bounds__(1024) void k_fused(const float* __restrict__ z,
                                                const float* __restrict__ V,
                                                const float* __restrict__ temp,
                                                float* __restrict__ out) {
    const int b   = blockIdx.x >> 5;
    const int s   = blockIdx.x & (NSLICE - 1);
    const int tid = threadIdx.x;

    __shared__ unsigned int codes_u[NPOS / 4];   // 4 KB (4 packed codes / u32)
    __shared__ int h[NCODE];                     // 1 KB
    __shared__ float T[NCODE * (DV + 1)];        // 33.8 KB, stride 33

    if (tid < NCODE) h[tid] = 0;
    __syncthreads();

    // ---- A: codes + histogram (1024 threads x 4 positions) ----
    {
        const float4* z4 = (const float4*)(z + (size_t)b * KBITS * NPOS);
        unsigned int c0 = 0, c1 = 0, c2 = 0, c3 = 0;
#pragma unroll
        for (int bit = 0; bit < KBITS; ++bit) {
            const float4 f = z4[bit * (NPOS / 4) + tid];
            c0 |= (unsigned)(f.x > 0.5f) << bit;
            c1 |= (unsigned)(f.y > 0.5f) << bit;
            c2 |= (unsigned)(f.z > 0.5f) << bit;
            c3 |= (unsigned)(f.w > 0.5f) << bit;
        }
        codes_u[tid] = c0 | (c1 << 8) | (c2 << 16) | (c3 << 24);
        atomicAdd(&h[c0], 1);
        atomicAdd(&h[c1], 1);
        atomicAdd(&h[c2], 1);
        atomicAdd(&h[c3], 1);
    }
    __syncthreads();

    // ---- B: per-lane seeds ----
    const int d = tid >> 5;          // d-column owned by this half-wave
    const int l = tid & 31;          // v-block: v = 8l..8l+7
    const float a = __expf(-1.0f / fmaxf(temp[0], 0.1f));

    float val[8], cnt[8];
#pragma unroll
    for (int j = 0; j < 8; ++j) {
        const int v = l * 8 + j;
        const float c = (float)h[v];
        cnt[j] = c;
        val[j] = c * V[v * DV + d];  // V is 32 KB -> L1-resident
    }

    // ---- C: butterfly stages 0..2 in registers ----
#pragma unroll
    for (int st = 0; st < 3; ++st) {
        const int m = 1 << st;
#pragma unroll
        for (int j = 0; j < 8; ++j) {
            if ((j & m) == 0) {
                const int j1 = j | m;
                const float v0 = val[j], v1 = val[j1];
                val[j]  = fmaf(a, v1, v0);
                val[j1] = fmaf(a, v0, v1);
                const float s0 = cnt[j], s1 = cnt[j1];
                cnt[j]  = fmaf(a, s1, s0);
                cnt[j1] = fmaf(a, s0, s1);
            }
        }
    }
    // ---- C: stages 3..7 via shuffle (masks 1..16 stay inside half-wave) ----
#pragma unroll
    for (int st = 0; st < 5; ++st) {
        const int m = 1 << st;
#pragma unroll
        for (int j = 0; j < 8; ++j) {
            const float pv = __shfl_xor(val[j], m);
            val[j] = fmaf(a, pv, val[j]);
            const float pc = __shfl_xor(cnt[j], m);
            cnt[j] = fmaf(a, pc, cnt[j]);
        }
    }

    // ---- D: lane-local normalize, write table to LDS ----
#pragma unroll
    for (int j = 0; j < 8; ++j) {
        const int c = l * 8 + j;
        T[c * (DV + 1) + d] = val[j] / cnt[j];
    }
    __syncthreads();

    // ---- E: gather + one float4 store per thread ----
    {
        const unsigned char* cb = (const unsigned char*)codes_u;
        const int ng   = tid & 31;             // float4 index within slice
        const int base = s * 128 + ng * 4;     // n offset of this float4
        const uchar4 cc = *(const uchar4*)(cb + base);
        float4 r;
        r.x = T[cc.x * (DV + 1) + d];
        r.y = T[cc.y * (DV + 1) + d];
        r.z = T[cc.z * (DV + 1) + d];
        r.w = T[cc.w * (DV + 1) + d];
        float4* o4 = (float4*)(out + (size_t)(b * DV + d) * NPOS + base);
        *o4 = r;
    }
}

// ---------------------------------------------------------------------------
extern "C" void kernel_launch(void* const* d_in, const int* in_sizes, int n_in,
                              void* d_out, int out_size, void* d_ws, size_t ws_size,
                              hipStream_t stream) {
    const float* z    = (const float*)d_in[0];   // (B,8,64,64) fp32
    const float* temp = (const float*)d_in[1];   // scalar
    const float* V    = (const float*)d_in[2];   // (256,32) fp32
    float* out        = (float*)d_out;           // (B,32,64,64) fp32

    k_fused<<<B_SZ * NSLICE, 1024, 0, stream>>>(z, V, temp, out);
}